// Round 7
// baseline (555.520 us; speedup 1.0000x reference)
//
#include <hip/hip_runtime.h>
#include <hip/hip_bf16.h>
#include <stdint.h>

// Problem constants (fixed by the reference)
#define N_EDGES   800000
#define N_NODESC  50000
#define HID       128

typedef __attribute__((ext_vector_type(8))) short bf16x8;  // 8 bf16 = 4 VGPRs (MFMA A/B frag)
typedef __attribute__((ext_vector_type(4))) float f32x4;   // MFMA C/D frag
typedef __attribute__((ext_vector_type(4))) unsigned int u32x4;

__device__ __forceinline__ short f2bf(float f) {
    union { float f; uint32_t u; } v; v.f = f;
    uint32_t r = v.u + 0x7FFFu + ((v.u >> 16) & 1u);   // round-to-nearest-even
    return (short)(r >> 16);
}

// pack two f32 -> bf16x2 (RNE) via native v_cvt_pk_bf16_f32 on gfx950
__device__ __forceinline__ uint32_t packbf2(float lo, float hi) {
    float2 t; t.x = lo; t.y = hi;
    __hip_bfloat162 h = __float22bfloat162_rn(t);
    uint32_t u;
    __builtin_memcpy(&u, &h, 4);       // __hip_bfloat162 not trivially copyable -> memcpy pun
    return u;
}

// packed bf16x2 (a+b) then relu: native v_pk_add_bf16 (one RNE rounding) + sign-mask relu
__device__ __forceinline__ uint32_t addrelu2(uint32_t a, uint32_t b) {
    __hip_bfloat162 ha, hb;
    __builtin_memcpy(&ha, &a, 4);
    __builtin_memcpy(&hb, &b, 4);
    __hip_bfloat162 s = __hadd2(ha, hb);
    uint32_t x;
    __builtin_memcpy(&x, &s, 4);
    uint32_t neg = (x & 0x80008000u) >> 15;      // 1 at bit0/bit16 where half negative
    return x & ~(neg * 0xFFFFu);                 // zero negative halves
}
__device__ __forceinline__ bf16x8 addrelu8(u32x4 p, u32x4 q) {
    u32x4 r;
    #pragma unroll
    for (int j = 0; j < 4; ++j) r[j] = addrelu2(p[j], q[j]);
    bf16x8 out;
    __builtin_memcpy(&out, &r, 16);
    return out;
}

// ---------------- workspace layout ----------------
// PQ  : bf16 [50000][1024]  (cols 0..511 = emb@W1_top + b1 "P'", 512..1023 = emb@W1_bot "Q")
// W1s : bf16 frag-major, 4*64 frags x 64 lanes x 8   (B-frags of W1cat [128,1024])
// W2s : bf16 frag-major, 16*8 frags x 64 lanes x 8   (B-frags of W2 [512,128])
// cnt/cursor : int[50000] histogram / scatter cursors for counting sort by col
// col_s/row_s/e_s : int[800000] edges sorted by col (SoA)
#define PQ_OFF    0UL
#define W1S_OFF   102400000UL                 // 50000*1024*2
#define W2S_OFF   (W1S_OFF + 262144UL)        // + 128*1024*2
#define CNT_OFF   (W2S_OFF + 131072UL)
#define CUR_OFF   (CNT_OFF + 200000UL)
#define COLS_OFF  (CUR_OFF + 200000UL)
#define ROWS_OFF  (COLS_OFF + 3200000UL)
#define ES_OFF    (ROWS_OFF + 3200000UL)
// total ws needed: ES_OFF + 3200000 = 112,793,216 bytes

// ============ kernel 0: weight convert + B-fragment swizzle ============
// B-frag for 16x16x32 bf16: lane l holds B[k = kc*32 + (l>>4)*8 + j][n = nt*16 + (l&15)], j=0..7
__global__ __launch_bounds__(256) void swizzle_kernel(const float* __restrict__ W1,
                                                      const float* __restrict__ W2,
                                                      short* __restrict__ W1s,
                                                      short* __restrict__ W2s) {
    int t = blockIdx.x * 256 + threadIdx.x;
    int lane = t & 63;
    int kq = lane >> 4;       // 0..3
    int nn = lane & 15;
    if (t < 16384) {          // W1cat: K=128, N=1024 -> kc 0..3, nt 0..63
        int frag = t >> 6;
        int kc = frag >> 6;
        int nt = frag & 63;
        int n = nt * 16 + nn;
        int kbase = kc * 32 + kq * 8;
        bf16x8 v;
        #pragma unroll
        for (int j = 0; j < 8; ++j) {
            int k = kbase + j;
            float f = (n < 512) ? W1[k * 512 + n] : W1[(128 + k) * 512 + (n - 512)];
            v[j] = f2bf(f);
        }
        *(bf16x8*)(W1s + frag * 512 + lane * 8) = v;
    } else if (t < 24576) {   // W2: K=512, N=128 -> kc 0..15, nt 0..7
        int t2 = t - 16384;
        int frag = t2 >> 6;
        int kc = frag >> 3;
        int nt = frag & 7;
        int n = nt * 16 + nn;
        int kbase = kc * 32 + kq * 8;
        bf16x8 v;
        #pragma unroll
        for (int j = 0; j < 8; ++j) v[j] = f2bf(W2[(kbase + j) * HID + n]);
        *(bf16x8*)(W2s + frag * 512 + lane * 8) = v;
    }
}

// ============ counting sort by col: hist -> scan -> scatter ============
__global__ __launch_bounds__(256) void hist_kernel(const int* __restrict__ ei,
                                                   int* __restrict__ cnt) {
    int e = blockIdx.x * 256 + threadIdx.x;
    atomicAdd(&cnt[ei[e]], 1);
}

// single block, 1024 threads: exclusive prefix over 50000 counts -> cursor
__global__ __launch_bounds__(1024) void scan_kernel(const int* __restrict__ cnt,
                                                    int* __restrict__ cursor) {
    __shared__ int psum[1024];
    int tid = threadIdx.x;
    int lo = tid * 49;
    int hi = lo + 49; if (hi > N_NODESC) hi = N_NODESC;
    int s = 0;
    for (int i = lo; i < hi; ++i) s += cnt[i];
    psum[tid] = s;
    __syncthreads();
    if (tid == 0) {
        int acc = 0;
        for (int i = 0; i < 1024; ++i) { int t = psum[i]; psum[i] = acc; acc += t; }
    }
    __syncthreads();
    int run = psum[tid];
    for (int i = lo; i < hi; ++i) { int c = cnt[i]; cursor[i] = run; run += c; }
}

__global__ __launch_bounds__(256) void scatter_kernel(const int* __restrict__ ei,
                                                      int* __restrict__ cursor,
                                                      int* __restrict__ col_s,
                                                      int* __restrict__ row_s,
                                                      int* __restrict__ e_s) {
    int e = blockIdx.x * 256 + threadIdx.x;
    int c = ei[e];
    int r = ei[N_EDGES + e];
    int slot = atomicAdd(&cursor[c], 1);
    col_s[slot] = c; row_s[slot] = r; e_s[slot] = e;
}

// ============ kernel 1: PQ = emb @ W1cat (+b1 on P half) ============
// grid 1563 x 256: block = 32 node rows (2 m-tiles/wave halves W1s L2 re-reads to 400 MB),
// 4 waves each owning a 256-col slice.  C-tile -> per-wave LDS transpose -> coalesced
// dwordx4 PQ stores (the R6 fix; wave-private tile, no barriers).
__global__ __launch_bounds__(256) void precompute_kernel(const float* __restrict__ emb,
                                                         const short* __restrict__ W1s,
                                                         const float* __restrict__ b1,
                                                         short* __restrict__ PQ) {
    __shared__ short tile[4][16][272];   // 16 rows x 256 cols, stride 272 shorts (544 B)
    int lane = threadIdx.x & 63;
    int w = threadIdx.x >> 6;
    int nb = blockIdx.x * 32;
    int m = lane & 15;
    int kq = lane >> 4;

    int n0 = nb + m;       if (n0 > N_NODESC - 1) n0 = N_NODESC - 1;   // clamp OOB loads
    int n1 = nb + 16 + m;  if (n1 > N_NODESC - 1) n1 = N_NODESC - 1;
    const float* a0p = emb + (size_t)n0 * 128 + kq * 8;
    const float* a1p = emb + (size_t)n1 * 128 + kq * 8;

    f32x4 acc[2][16];
    #pragma unroll
    for (int mt = 0; mt < 2; ++mt)
        #pragma unroll
        for (int i = 0; i < 16; ++i) acc[mt][i] = (f32x4){0.f, 0.f, 0.f, 0.f};

    #pragma unroll
    for (int kc = 0; kc < 4; ++kc) {
        f32x4 x0 = *(const f32x4*)(a0p + kc * 32);
        f32x4 x1 = *(const f32x4*)(a0p + kc * 32 + 4);
        f32x4 y0 = *(const f32x4*)(a1p + kc * 32);
        f32x4 y1 = *(const f32x4*)(a1p + kc * 32 + 4);
        u32x4 au, bu;
        au[0] = packbf2(x0[0], x0[1]); au[1] = packbf2(x0[2], x0[3]);
        au[2] = packbf2(x1[0], x1[1]); au[3] = packbf2(x1[2], x1[3]);
        bu[0] = packbf2(y0[0], y0[1]); bu[1] = packbf2(y0[2], y0[3]);
        bu[2] = packbf2(y1[0], y1[1]); bu[3] = packbf2(y1[2], y1[3]);
        bf16x8 a0, a1;
        __builtin_memcpy(&a0, &au, 16);
        __builtin_memcpy(&a1, &bu, 16);
        #pragma unroll
        for (int nt = 0; nt < 16; ++nt) {
            int frag = kc * 64 + (w * 16 + nt);
            bf16x8 b = *(const bf16x8*)(W1s + frag * 512 + lane * 8);
            acc[0][nt] = __builtin_amdgcn_mfma_f32_16x16x32_bf16(a0, b, acc[0][nt], 0, 0, 0);
            acc[1][nt] = __builtin_amdgcn_mfma_f32_16x16x32_bf16(a1, b, acc[1][nt], 0, 0, 0);
        }
    }

    // C/D layout: col = lane&15, row = (lane>>4)*4 + r.  Fold b1 into the P half (n<512).
    #pragma unroll
    for (int mt = 0; mt < 2; ++mt) {
        #pragma unroll
        for (int nt = 0; nt < 16; ++nt) {
            int n = w * 256 + nt * 16 + m;
            float bias = (n < 512) ? b1[n] : 0.0f;
            #pragma unroll
            for (int r = 0; r < 4; ++r)
                tile[w][kq * 4 + r][nt * 16 + m] = f2bf(acc[mt][nt][r] + bias);
        }
        // coalesced store: 16 B/lane, two contiguous 512 B segments per inst
        #pragma unroll
        for (int s = 0; s < 8; ++s) {
            int row = s * 2 + (lane >> 5);
            int chunk = lane & 31;
            int node = nb + mt * 16 + row;
            bf16x8 v = *(const bf16x8*)(&tile[w][row][chunk * 8]);
            if (node < N_NODESC)
                *(bf16x8*)(PQ + (size_t)node * 1024 + w * 256 + chunk * 8) = v;
        }
    }
}

// ============ kernel 2: per-edge fused MLP on col-sorted edges ============
// grid 3125 x 256: each wave owns 64 SORTED edges (4 m-tiles).  Sorted by col ->
// ~4 distinct P rows per wave (L1-resident) and sequential PQ walk across waves.
// Structure otherwise identical to R5/R6 (best measured).  Output scattered via e_s.
__global__ __launch_bounds__(256, 2) void edge_kernel(const short* __restrict__ PQ,
                                                      const int* __restrict__ col_s,
                                                      const int* __restrict__ row_s,
                                                      const int* __restrict__ e_s,
                                                      const short* __restrict__ W2s,
                                                      const float* __restrict__ b2,
                                                      const float* __restrict__ W3,
                                                      const float* __restrict__ b3,
                                                      float* __restrict__ out) {
    int lane = threadIdx.x & 63;
    int w = threadIdx.x >> 6;
    int e0 = blockIdx.x * 256 + w * 64;
    int m = lane & 15;
    int kq = lane >> 4;

    int idx_c = col_s[e0 + lane];
    int idx_r = row_s[e0 + lane];

    const short* pb[4];
    const short* qb[4];
    #pragma unroll
    for (int t = 0; t < 4; ++t) {
        int ce = __shfl(idx_c, t * 16 + m, 64);
        int re = __shfl(idx_r, t * 16 + m, 64);
        pb[t] = PQ + (size_t)ce * 1024 + kq * 8;          // P' half
        qb[t] = PQ + (size_t)re * 1024 + 512 + kq * 8;    // Q half
    }

    f32x4 acc[4][8];
    #pragma unroll
    for (int t = 0; t < 4; ++t)
        #pragma unroll
        for (int nt = 0; nt < 8; ++nt) acc[t][nt] = (f32x4){0.f, 0.f, 0.f, 0.f};

    #pragma unroll
    for (int kc = 0; kc < 16; ++kc) {
        u32x4 p[4], q[4];
        #pragma unroll
        for (int t = 0; t < 4; ++t) {
            p[t] = *(const u32x4*)(pb[t] + kc * 32);
            q[t] = *(const u32x4*)(qb[t] + kc * 32);
        }
        bf16x8 b[8];
        #pragma unroll
        for (int nt = 0; nt < 8; ++nt)
            b[nt] = *(const bf16x8*)(W2s + (kc * 8 + nt) * 512 + lane * 8);
        #pragma unroll
        for (int t = 0; t < 4; ++t) {
            bf16x8 a = addrelu8(p[t], q[t]);
            #pragma unroll
            for (int nt = 0; nt < 8; ++nt)
                acc[t][nt] = __builtin_amdgcn_mfma_f32_16x16x32_bf16(a, b[nt], acc[t][nt], 0, 0, 0);
        }
    }

    // ---- epilogue: +b2, relu, dot with W3, +b3; scatter to out[e_s] ----
    int eid = e_s[e0 + lane];    // loaded late to keep main-loop reg pressure unchanged
    float b2v[8], w3v[8];
    #pragma unroll
    for (int nt = 0; nt < 8; ++nt) {
        b2v[nt] = b2[nt * 16 + m];
        w3v[nt] = W3[nt * 16 + m];
    }
    float b3s = b3[0];
    #pragma unroll
    for (int t = 0; t < 4; ++t) {
        float partial[4] = {0.f, 0.f, 0.f, 0.f};
        #pragma unroll
        for (int nt = 0; nt < 8; ++nt) {
            #pragma unroll
            for (int r = 0; r < 4; ++r) {
                float x2 = acc[t][nt][r] + b2v[nt];       // C row = kq*4+r, col = nt*16+m
                x2 = x2 > 0.f ? x2 : 0.f;
                partial[r] += x2 * w3v[nt];
            }
        }
        #pragma unroll
        for (int r = 0; r < 4; ++r) {
            #pragma unroll
            for (int off = 1; off < 16; off <<= 1)
                partial[r] += __shfl_xor(partial[r], off, 64);
            int eo = __shfl(eid, t * 16 + kq * 4 + r, 64);
            if (m == 0) out[eo] = partial[r] + b3s;
        }
    }
}

extern "C" void kernel_launch(void* const* d_in, const int* in_sizes, int n_in,
                              void* d_out, int out_size, void* d_ws, size_t ws_size,
                              hipStream_t stream) {
    const float* emb = (const float*)d_in[0];
    const int*   ei  = (const int*)d_in[1];
    const float* W1  = (const float*)d_in[2];
    const float* b1  = (const float*)d_in[3];
    const float* W2  = (const float*)d_in[4];
    const float* b2  = (const float*)d_in[5];
    const float* W3  = (const float*)d_in[6];
    const float* b3  = (const float*)d_in[7];
    float* out = (float*)d_out;

    short* PQ    = (short*)((char*)d_ws + PQ_OFF);
    short* W1s   = (short*)((char*)d_ws + W1S_OFF);
    short* W2s   = (short*)((char*)d_ws + W2S_OFF);
    int*   cnt   = (int*)((char*)d_ws + CNT_OFF);
    int*   cur   = (int*)((char*)d_ws + CUR_OFF);
    int*   col_s = (int*)((char*)d_ws + COLS_OFF);
    int*   row_s = (int*)((char*)d_ws + ROWS_OFF);
    int*   e_s   = (int*)((char*)d_ws + ES_OFF);

    hipMemsetAsync(cnt, 0, N_NODESC * sizeof(int), stream);
    swizzle_kernel<<<96, 256, 0, stream>>>(W1, W2, W1s, W2s);
    hist_kernel<<<N_EDGES / 256, 256, 0, stream>>>(ei, cnt);
    scan_kernel<<<1, 1024, 0, stream>>>(cnt, cur);
    scatter_kernel<<<N_EDGES / 256, 256, 0, stream>>>(ei, cur, col_s, row_s, e_s);
    precompute_kernel<<<(N_NODESC + 31) / 32, 256, 0, stream>>>(emb, W1s, b1, PQ);     // 1563 blocks
    edge_kernel<<<N_EDGES / 256, 256, 0, stream>>>(PQ, col_s, row_s, e_s,
                                                   W2s, b2, W3, b3, out);              // 3125 blocks
}

// Round 8
// 515.729 us; speedup vs baseline: 1.0772x; 1.0772x over previous
//
#include <hip/hip_runtime.h>
#include <hip/hip_bf16.h>
#include <stdint.h>

// Problem constants (fixed by the reference)
#define N_EDGES   800000
#define N_NODESC  50000
#define HID       128
#define NBUCK     (98 * 98)     // 2D buckets: (col>>9) x (row>>9), 98 each side

typedef __attribute__((ext_vector_type(8))) short bf16x8;  // 8 bf16 = 4 VGPRs (MFMA A/B frag)
typedef __attribute__((ext_vector_type(4))) float f32x4;   // MFMA C/D frag
typedef __attribute__((ext_vector_type(4))) unsigned int u32x4;

__device__ __forceinline__ short f2bf(float f) {
    union { float f; uint32_t u; } v; v.f = f;
    uint32_t r = v.u + 0x7FFFu + ((v.u >> 16) & 1u);   // round-to-nearest-even
    return (short)(r >> 16);
}

// pack two f32 -> bf16x2 (RNE) via native v_cvt_pk_bf16_f32 on gfx950
__device__ __forceinline__ uint32_t packbf2(float lo, float hi) {
    float2 t; t.x = lo; t.y = hi;
    __hip_bfloat162 h = __float22bfloat162_rn(t);
    uint32_t u;
    __builtin_memcpy(&u, &h, 4);       // __hip_bfloat162 not trivially copyable -> memcpy pun
    return u;
}

// packed bf16x2 (a+b) then relu: native v_pk_add_bf16 (one RNE rounding) + sign-mask relu
__device__ __forceinline__ uint32_t addrelu2(uint32_t a, uint32_t b) {
    __hip_bfloat162 ha, hb;
    __builtin_memcpy(&ha, &a, 4);
    __builtin_memcpy(&hb, &b, 4);
    __hip_bfloat162 s = __hadd2(ha, hb);
    uint32_t x;
    __builtin_memcpy(&x, &s, 4);
    uint32_t neg = (x & 0x80008000u) >> 15;      // 1 at bit0/bit16 where half negative
    return x & ~(neg * 0xFFFFu);                 // zero negative halves
}
__device__ __forceinline__ bf16x8 addrelu8(u32x4 p, u32x4 q) {
    u32x4 r;
    #pragma unroll
    for (int j = 0; j < 4; ++j) r[j] = addrelu2(p[j], q[j]);
    bf16x8 out;
    __builtin_memcpy(&out, &r, 16);
    return out;
}

// ---------------- workspace layout ----------------
// PQ  : bf16 [50000][1024]  (cols 0..511 = emb@W1_top + b1 "P'", 512..1023 = emb@W1_bot "Q")
// W1s : bf16 frag-major, 4*64 frags x 64 lanes x 8   (B-frags of W1cat [128,1024])
// W2s : bf16 frag-major, 16*8 frags x 64 lanes x 8   (B-frags of W2 [512,128])
// cnt/cursor : int[NBUCK] histogram / scatter cursors (2D coarse bucket sort)
// pk  : uint2[800000]  bucket-sorted edges, packed (col<<16|row, eid)
#define PQ_OFF    0UL
#define W1S_OFF   102400000UL                 // 50000*1024*2
#define W2S_OFF   (W1S_OFF + 262144UL)
#define CNT_OFF   (W2S_OFF + 131072UL)
#define CUR_OFF   (CNT_OFF + 40960UL)
#define PK_OFF    (CUR_OFF + 40960UL)
// total ws needed: PK_OFF + 6,400,000 = 109,275,136 bytes

// ============ kernel 0: weight convert + B-fragment swizzle ============
// B-frag for 16x16x32 bf16: lane l holds B[k = kc*32 + (l>>4)*8 + j][n = nt*16 + (l&15)], j=0..7
__global__ __launch_bounds__(256) void swizzle_kernel(const float* __restrict__ W1,
                                                      const float* __restrict__ W2,
                                                      short* __restrict__ W1s,
                                                      short* __restrict__ W2s) {
    int t = blockIdx.x * 256 + threadIdx.x;
    int lane = t & 63;
    int kq = lane >> 4;       // 0..3
    int nn = lane & 15;
    if (t < 16384) {          // W1cat: K=128, N=1024 -> kc 0..3, nt 0..63
        int frag = t >> 6;
        int kc = frag >> 6;
        int nt = frag & 63;
        int n = nt * 16 + nn;
        int kbase = kc * 32 + kq * 8;
        bf16x8 v;
        #pragma unroll
        for (int j = 0; j < 8; ++j) {
            int k = kbase + j;
            float f = (n < 512) ? W1[k * 512 + n] : W1[(128 + k) * 512 + (n - 512)];
            v[j] = f2bf(f);
        }
        *(bf16x8*)(W1s + frag * 512 + lane * 8) = v;
    } else if (t < 24576) {   // W2: K=512, N=128 -> kc 0..15, nt 0..7
        int t2 = t - 16384;
        int frag = t2 >> 6;
        int kc = frag >> 3;
        int nt = frag & 7;
        int n = nt * 16 + nn;
        int kbase = kc * 32 + kq * 8;
        bf16x8 v;
        #pragma unroll
        for (int j = 0; j < 8; ++j) v[j] = f2bf(W2[(kbase + j) * HID + n]);
        *(bf16x8*)(W2s + frag * 512 + lane * 8) = v;
    }
}

// ============ 2D coarse bucket sort: hist -> parallel scan -> packed scatter ============
__global__ __launch_bounds__(256) void hist_kernel(const int* __restrict__ ei,
                                                   int* __restrict__ cnt) {
    int e = blockIdx.x * 256 + threadIdx.x;
    int c = ei[e];
    int r = ei[N_EDGES + e];
    atomicAdd(&cnt[(c >> 9) * 98 + (r >> 9)], 1);
}

// single block, 1024 threads: exclusive scan of NBUCK counts, all-parallel
// (shuffle scan — no serial LDS chain, the R7 scan's ~100 us bug)
__global__ __launch_bounds__(1024) void scan_kernel(const int* __restrict__ cnt,
                                                    int* __restrict__ cursor) {
    __shared__ int wsum[16];
    int tid = threadIdx.x;
    int lane = tid & 63, wv = tid >> 6;
    const int CH = (NBUCK + 1023) / 1024;    // 10
    int lo = tid * CH;
    int local[CH];
    int s = 0;
    #pragma unroll
    for (int i = 0; i < CH; ++i) {
        int idx = lo + i;
        int v = (idx < NBUCK) ? cnt[idx] : 0;
        local[i] = v; s += v;
    }
    // inclusive shuffle scan across 64 lanes
    int run = s;
    #pragma unroll
    for (int off = 1; off < 64; off <<= 1) {
        int t = __shfl_up(run, off, 64);
        if (lane >= off) run += t;
    }
    if (lane == 63) wsum[wv] = run;
    __syncthreads();
    if (wv == 0 && lane < 16) {
        int v = wsum[lane];
        int r2 = v;
        #pragma unroll
        for (int off = 1; off < 16; off <<= 1) {
            int t = __shfl_up(r2, off, 64);
            if (lane >= off) r2 += t;
        }
        wsum[lane] = r2 - v;                 // exclusive wave offsets
    }
    __syncthreads();
    int base = wsum[wv] + (run - s);         // exclusive prefix for this thread
    #pragma unroll
    for (int i = 0; i < CH; ++i) {
        int idx = lo + i;
        if (idx < NBUCK) { cursor[idx] = base; base += local[i]; }
    }
}

__global__ __launch_bounds__(256) void scatter_kernel(const int* __restrict__ ei,
                                                      int* __restrict__ cursor,
                                                      uint2* __restrict__ pk) {
    int e = blockIdx.x * 256 + threadIdx.x;
    int c = ei[e];
    int r = ei[N_EDGES + e];
    int slot = atomicAdd(&cursor[(c >> 9) * 98 + (r >> 9)], 1);
    uint2 v;
    v.x = ((uint32_t)c << 16) | (uint32_t)r;   // both < 65536
    v.y = (uint32_t)e;
    pk[slot] = v;                               // single 8 B scattered write
}

// ============ kernel 1: PQ = emb @ W1cat (+b1 on P half) — exact R6 version ============
// grid 3125 x 256: block = 16 node rows, 4 waves each owning a 256-col slice.
// C-tile -> per-wave LDS transpose -> coalesced dwordx4 stores (no barriers).
__global__ __launch_bounds__(256) void precompute_kernel(const float* __restrict__ emb,
                                                         const short* __restrict__ W1s,
                                                         const float* __restrict__ b1,
                                                         short* __restrict__ PQ) {
    __shared__ short tile[4][16][272];   // 16 rows x 256 cols, stride 272 shorts (544 B)
    int lane = threadIdx.x & 63;
    int w = threadIdx.x >> 6;
    int nb = blockIdx.x * 16;
    int m = lane & 15;
    int kq = lane >> 4;

    const float* arow = emb + (size_t)(nb + m) * 128 + kq * 8;

    f32x4 acc[16];
    #pragma unroll
    for (int i = 0; i < 16; ++i) acc[i] = (f32x4){0.f, 0.f, 0.f, 0.f};

    #pragma unroll
    for (int kc = 0; kc < 4; ++kc) {
        f32x4 x0 = *(const f32x4*)(arow + kc * 32);
        f32x4 x1 = *(const f32x4*)(arow + kc * 32 + 4);
        u32x4 au;
        au[0] = packbf2(x0[0], x0[1]); au[1] = packbf2(x0[2], x0[3]);
        au[2] = packbf2(x1[0], x1[1]); au[3] = packbf2(x1[2], x1[3]);
        bf16x8 a;
        __builtin_memcpy(&a, &au, 16);
        #pragma unroll
        for (int nt = 0; nt < 16; ++nt) {
            int frag = kc * 64 + (w * 16 + nt);
            bf16x8 b = *(const bf16x8*)(W1s + frag * 512 + lane * 8);
            acc[nt] = __builtin_amdgcn_mfma_f32_16x16x32_bf16(a, b, acc[nt], 0, 0, 0);
        }
    }

    // C/D layout: col = lane&15, row = (lane>>4)*4 + r.  Fold b1 into the P half (n<512).
    #pragma unroll
    for (int nt = 0; nt < 16; ++nt) {
        int n = w * 256 + nt * 16 + m;
        float bias = (n < 512) ? b1[n] : 0.0f;
        #pragma unroll
        for (int r = 0; r < 4; ++r)
            tile[w][kq * 4 + r][nt * 16 + m] = f2bf(acc[nt][r] + bias);
    }

    #pragma unroll
    for (int s = 0; s < 8; ++s) {
        int row = s * 2 + (lane >> 5);
        int chunk = lane & 31;
        bf16x8 v = *(const bf16x8*)(&tile[w][row][chunk * 8]);
        *(bf16x8*)(PQ + (size_t)(nb + row) * 1024 + w * 256 + chunk * 8) = v;
    }
}

// ============ kernel 2: per-edge fused MLP on 2D-bucket-sorted edges ============
// grid 3125 x 256: each wave owns 64 sorted edges (4 m-tiles).  Bucketing makes both
// P and Q gathers walk ~512 KB L2-resident windows.  Output scattered via packed eid.
__global__ __launch_bounds__(256, 2) void edge_kernel(const short* __restrict__ PQ,
                                                      const uint2* __restrict__ pk,
                                                      const short* __restrict__ W2s,
                                                      const float* __restrict__ b2,
                                                      const float* __restrict__ W3,
                                                      const float* __restrict__ b3,
                                                      float* __restrict__ out) {
    int lane = threadIdx.x & 63;
    int w = threadIdx.x >> 6;
    int e0 = blockIdx.x * 256 + w * 64;
    int m = lane & 15;
    int kq = lane >> 4;

    uint2 pe = pk[e0 + lane];
    int idx_c = (int)(pe.x >> 16);
    int idx_r = (int)(pe.x & 0xFFFFu);
    int eid   = (int)pe.y;

    const short* pb[4];
    const short* qb[4];
    #pragma unroll
    for (int t = 0; t < 4; ++t) {
        int ce = __shfl(idx_c, t * 16 + m, 64);
        int re = __shfl(idx_r, t * 16 + m, 64);
        pb[t] = PQ + (size_t)ce * 1024 + kq * 8;          // P' half
        qb[t] = PQ + (size_t)re * 1024 + 512 + kq * 8;    // Q half
    }

    f32x4 acc[4][8];
    #pragma unroll
    for (int t = 0; t < 4; ++t)
        #pragma unroll
        for (int nt = 0; nt < 8; ++nt) acc[t][nt] = (f32x4){0.f, 0.f, 0.f, 0.f};

    #pragma unroll
    for (int kc = 0; kc < 16; ++kc) {
        u32x4 p[4], q[4];
        #pragma unroll
        for (int t = 0; t < 4; ++t) {
            p[t] = *(const u32x4*)(pb[t] + kc * 32);
            q[t] = *(const u32x4*)(qb[t] + kc * 32);
        }
        bf16x8 b[8];
        #pragma unroll
        for (int nt = 0; nt < 8; ++nt)
            b[nt] = *(const bf16x8*)(W2s + (kc * 8 + nt) * 512 + lane * 8);
        #pragma unroll
        for (int t = 0; t < 4; ++t) {
            bf16x8 a = addrelu8(p[t], q[t]);
            #pragma unroll
            for (int nt = 0; nt < 8; ++nt)
                acc[t][nt] = __builtin_amdgcn_mfma_f32_16x16x32_bf16(a, b[nt], acc[t][nt], 0, 0, 0);
        }
    }

    // ---- epilogue: +b2, relu, dot with W3, +b3; scatter to out[eid] ----
    float b2v[8], w3v[8];
    #pragma unroll
    for (int nt = 0; nt < 8; ++nt) {
        b2v[nt] = b2[nt * 16 + m];
        w3v[nt] = W3[nt * 16 + m];
    }
    float b3s = b3[0];
    #pragma unroll
    for (int t = 0; t < 4; ++t) {
        float partial[4] = {0.f, 0.f, 0.f, 0.f};
        #pragma unroll
        for (int nt = 0; nt < 8; ++nt) {
            #pragma unroll
            for (int r = 0; r < 4; ++r) {
                float x2 = acc[t][nt][r] + b2v[nt];       // C row = kq*4+r, col = nt*16+m
                x2 = x2 > 0.f ? x2 : 0.f;
                partial[r] += x2 * w3v[nt];
            }
        }
        #pragma unroll
        for (int r = 0; r < 4; ++r) {
            #pragma unroll
            for (int off = 1; off < 16; off <<= 1)
                partial[r] += __shfl_xor(partial[r], off, 64);
            int eo = __shfl(eid, t * 16 + kq * 4 + r, 64);
            if (m == 0) out[eo] = partial[r] + b3s;
        }
    }
}

extern "C" void kernel_launch(void* const* d_in, const int* in_sizes, int n_in,
                              void* d_out, int out_size, void* d_ws, size_t ws_size,
                              hipStream_t stream) {
    const float* emb = (const float*)d_in[0];
    const int*   ei  = (const int*)d_in[1];
    const float* W1  = (const float*)d_in[2];
    const float* b1  = (const float*)d_in[3];
    const float* W2  = (const float*)d_in[4];
    const float* b2  = (const float*)d_in[5];
    const float* W3  = (const float*)d_in[6];
    const float* b3  = (const float*)d_in[7];
    float* out = (float*)d_out;

    short* PQ  = (short*)((char*)d_ws + PQ_OFF);
    short* W1s = (short*)((char*)d_ws + W1S_OFF);
    short* W2s = (short*)((char*)d_ws + W2S_OFF);
    int*   cnt = (int*)((char*)d_ws + CNT_OFF);
    int*   cur = (int*)((char*)d_ws + CUR_OFF);
    uint2* pk  = (uint2*)((char*)d_ws + PK_OFF);

    hipMemsetAsync(cnt, 0, NBUCK * sizeof(int), stream);
    swizzle_kernel<<<96, 256, 0, stream>>>(W1, W2, W1s, W2s);
    hist_kernel<<<N_EDGES / 256, 256, 0, stream>>>(ei, cnt);
    scan_kernel<<<1, 1024, 0, stream>>>(cnt, cur);
    scatter_kernel<<<N_EDGES / 256, 256, 0, stream>>>(ei, cur, pk);
    precompute_kernel<<<N_NODESC / 16, 256, 0, stream>>>(emb, W1s, b1, PQ);            // 3125 blocks
    edge_kernel<<<N_EDGES / 256, 256, 0, stream>>>(PQ, pk, W2s, b2, W3, b3, out);      // 3125 blocks
}